// Round 2
// baseline (145.215 us; speedup 1.0000x reference)
//
#include <hip/hip_runtime.h>

// DDPM fused forward: per-sample 3x3 circular blur -> conv1(1->64) + t -> relu
// -> conv2(64->1) -> MSE vs original x.  B=64, C=1, H=W=128, HID=64.
//
// Grid: 64 samples x 4 tiles (64x64) = 256 blocks (1/CU), 256 threads.
// Each thread computes a 4x4 output patch; the 64-channel loop is fully
// register-resident (8x8 blurred patch in VGPRs, weights via uniform scalar
// loads) -> no LDS traffic and no barrier in the hot loop.
//
// Border handling: conv1/conv2 use SAME zero padding. Blur values outside the
// image are zeroed in LDS (phase B). h values outside the image are killed by
// biasing their pre-relu init with -1e30 (fmax(vv,0) -> 0), which replaces the
// 2-multiply mask of the previous revision.

#define XS_W 72   // 70x70 x-tile (halo 3), padded stride
#define XB_W 72   // 68x68 blurred tile (halo 2), stride padded to 16B multiple

__global__ __launch_bounds__(256, 1) void ddpm_fused(
    const float* __restrict__ x, const int* __restrict__ t,
    const float* __restrict__ kernels, const float* __restrict__ w1,
    const float* __restrict__ b1, const float* __restrict__ w2,
    const float* __restrict__ b2, float* __restrict__ out)
{
    __shared__ __align__(16) float xs[70][XS_W];
    __shared__ __align__(16) float xb[68][XB_W];
    __shared__ float redbuf[4];

    const int bid = blockIdx.x;
    const int s   = bid >> 2;         // sample
    const int tt  = bid & 3;          // tile within sample (2x2 of 64x64)
    const int ty  = (tt >> 1) * 64;
    const int tx  = (tt & 1) * 64;
    const int tid = threadIdx.x;

    const float* __restrict__ xsamp = x + s * (128 * 128);

    // ---- block-uniform scalars ----
    const int   tb = t[s];
    const float tn = (float)(tb + 1) * 0.01f;           // (t+1)/n_T
    const float* __restrict__ kb = kernels + tb * 9;
    const float k0 = kb[0], k1 = kb[1], k2 = kb[2],
                k3 = kb[3], k4 = kb[4], k5 = kb[5],
                k6 = kb[6], k7 = kb[7], k8 = kb[8];

    // ---- phase A: stage x tile + halo 3 (circular wrap; 128 = pow2) ----
    for (int i = tid; i < 70 * 70; i += 256) {
        int r = i / 70, c = i - r * 70;
        int gy = (ty + r - 3) & 127;
        int gx = (tx + c - 3) & 127;
        xs[r][c] = xsamp[gy * 128 + gx];
    }
    __syncthreads();

    // ---- phase B: blur -> xb (tile-local rows -2..65), zero outside image ----
    for (int i = tid; i < 68 * 68; i += 256) {
        int r = i / 68, c = i - r * 68;
        int gy = ty + r - 2, gx = tx + c - 2;
        float v = 0.f;
        if (gy >= 0 && gy < 128 && gx >= 0 && gx < 128) {
            v = k0 * xs[r    ][c] + k1 * xs[r    ][c + 1] + k2 * xs[r    ][c + 2]
              + k3 * xs[r + 1][c] + k4 * xs[r + 1][c + 1] + k5 * xs[r + 1][c + 2]
              + k6 * xs[r + 2][c] + k7 * xs[r + 2][c + 1] + k8 * xs[r + 2][c + 2];
        }
        xb[r][c] = v;
    }
    __syncthreads();

    // ---- phase C: per-thread 8x8 blurred patch into registers (b128 reads) ----
    const int ry = tid >> 4, rx = tid & 15;   // 16x16 thread grid
    const int py0 = ry * 4, px0 = rx * 4;     // tile-local output origin

    float rxb[8][8];
#pragma unroll
    for (int i = 0; i < 8; ++i) {
        const float4 lo = *reinterpret_cast<const float4*>(&xb[py0 + i][px0]);
        const float4 hi = *reinterpret_cast<const float4*>(&xb[py0 + i][px0 + 4]);
        rxb[i][0] = lo.x; rxb[i][1] = lo.y; rxb[i][2] = lo.z; rxb[i][3] = lo.w;
        rxb[i][4] = hi.x; rxb[i][5] = hi.y; rxb[i][6] = hi.z; rxb[i][7] = hi.w;
    }

    // h-position validity as additive bias: valid -> 0, invalid -> -1e30
    // (h local (i,j) sits at global (ty+py0-1+i, tx+px0-1+j))
    float rowneg[6], colneg[6];
#pragma unroll
    for (int i = 0; i < 6; ++i) {
        int gy = ty + py0 - 1 + i;
        rowneg[i] = (gy >= 0 && gy < 128) ? 0.f : -1e30f;
        int gx = tx + px0 - 1 + i;
        colneg[i] = (gx >= 0 && gx < 128) ? 0.f : -1e30f;
    }

    float acc[4][4];
#pragma unroll
    for (int a = 0; a < 4; ++a)
#pragma unroll
        for (int b_ = 0; b_ < 4; ++b_) acc[a][b_] = 0.f;

    // ---- channel loop: fully register-resident ----
#pragma unroll 1
    for (int c = 0; c < 64; ++c) {
        const float* __restrict__ w1c = w1 + c * 9;
        const float* __restrict__ w2c = w2 + c * 9;
        const float hinit = b1[c] + tn;
        const float u0 = w1c[0], u1 = w1c[1], u2 = w1c[2],
                    u3 = w1c[3], u4 = w1c[4], u5 = w1c[5],
                    u6 = w1c[6], u7 = w1c[7], u8 = w1c[8];
        const float v0 = w2c[0], v1 = w2c[1], v2 = w2c[2],
                    v3 = w2c[3], v4 = w2c[4], v5 = w2c[5],
                    v6 = w2c[6], v7 = w2c[7], v8 = w2c[8];

        float h[6][6];
#pragma unroll
        for (int i = 0; i < 6; ++i) {
            const float hb_i = hinit + rowneg[i];
#pragma unroll
            for (int j = 0; j < 6; ++j) {
                float vv = hb_i + colneg[j];
                vv += u0 * rxb[i    ][j] + u1 * rxb[i    ][j + 1] + u2 * rxb[i    ][j + 2];
                vv += u3 * rxb[i + 1][j] + u4 * rxb[i + 1][j + 1] + u5 * rxb[i + 1][j + 2];
                vv += u6 * rxb[i + 2][j] + u7 * rxb[i + 2][j + 1] + u8 * rxb[i + 2][j + 2];
                h[i][j] = fmaxf(vv, 0.f);   // invalid positions: vv ~ -1e30 -> 0
            }
        }
#pragma unroll
        for (int oy = 0; oy < 4; ++oy) {
#pragma unroll
            for (int ox = 0; ox < 4; ++ox) {
                float a = acc[oy][ox];
                a += v0 * h[oy    ][ox] + v1 * h[oy    ][ox + 1] + v2 * h[oy    ][ox + 2];
                a += v3 * h[oy + 1][ox] + v4 * h[oy + 1][ox + 1] + v5 * h[oy + 1][ox + 2];
                a += v6 * h[oy + 2][ox] + v7 * h[oy + 2][ox + 1] + v8 * h[oy + 2][ox + 2];
                acc[oy][ox] = a;
            }
        }
    }

    // ---- epilogue: MSE vs original x (still in xs), block reduce ----
    const float b2v = b2[0];
    float sum = 0.f;
#pragma unroll
    for (int oy = 0; oy < 4; ++oy)
#pragma unroll
        for (int ox = 0; ox < 4; ++ox) {
            float recon = acc[oy][ox] + b2v;
            float xv = xs[py0 + oy + 3][px0 + ox + 3];
            float d = xv - recon;
            sum += d * d;
        }

#pragma unroll
    for (int off = 32; off > 0; off >>= 1)
        sum += __shfl_down(sum, off, 64);

    const int lane = tid & 63, wv = tid >> 6;
    if (lane == 0) redbuf[wv] = sum;
    __syncthreads();
    if (tid == 0) {
        float tot = redbuf[0] + redbuf[1] + redbuf[2] + redbuf[3];
        atomicAdd(out, tot * (1.f / 1048576.f));   // /(64*128*128)
    }
}

extern "C" void kernel_launch(void* const* d_in, const int* in_sizes, int n_in,
                              void* d_out, int out_size, void* d_ws, size_t ws_size,
                              hipStream_t stream) {
    const float* x       = (const float*)d_in[0];
    const int*   t       = (const int*)  d_in[1];
    const float* kernels = (const float*)d_in[2];
    const float* w1      = (const float*)d_in[3];
    const float* b1      = (const float*)d_in[4];
    const float* w2      = (const float*)d_in[5];
    const float* b2      = (const float*)d_in[6];
    float* out = (float*)d_out;

    hipMemsetAsync(out, 0, sizeof(float), stream);
    ddpm_fused<<<256, 256, 0, stream>>>(x, t, kernels, w1, b1, w2, b2, out);
}

// Round 6
// 138.195 us; speedup vs baseline: 1.0508x; 1.0508x over previous
//
#include <hip/hip_runtime.h>

// DDPM fused forward: per-sample 3x3 circular blur -> conv1(1->64) + t -> relu
// -> conv2(64->1) -> MSE vs original x.  B=64, C=1, H=W=128, HID=64.
//
// Grid: 64 samples x 4 tiles (64x64) = 256 blocks (1/CU), 256 threads.
// Each thread computes a 4x4 output patch; the 64-channel loop is fully
// register-resident. R2 change: every MAC is an explicit fmaf() (R1 counters
// showed ~2x the modeled VALU busy-time -> compiler was emitting separate
// v_mul+v_add), and the channel loop is unrolled x2 to hide s_load latency.

#define XS_W 72   // 70x70 x-tile (halo 3), padded stride
#define XB_W 72   // 68x68 blurred tile (halo 2), stride padded to 16B multiple

__global__ __launch_bounds__(256, 1) void ddpm_fused(
    const float* __restrict__ x, const int* __restrict__ t,
    const float* __restrict__ kernels, const float* __restrict__ w1,
    const float* __restrict__ b1, const float* __restrict__ w2,
    const float* __restrict__ b2, float* __restrict__ out)
{
    __shared__ __align__(16) float xs[70][XS_W];
    __shared__ __align__(16) float xb[68][XB_W];
    __shared__ float redbuf[4];

    const int bid = blockIdx.x;
    const int s   = bid >> 2;         // sample
    const int tt  = bid & 3;          // tile within sample (2x2 of 64x64)
    const int ty  = (tt >> 1) * 64;
    const int tx  = (tt & 1) * 64;
    const int tid = threadIdx.x;

    const float* __restrict__ xsamp = x + s * (128 * 128);

    // ---- block-uniform scalars ----
    const int   tb = t[s];
    const float tn = (float)(tb + 1) * 0.01f;           // (t+1)/n_T
    const float* __restrict__ kb = kernels + tb * 9;
    const float k0 = kb[0], k1 = kb[1], k2 = kb[2],
                k3 = kb[3], k4 = kb[4], k5 = kb[5],
                k6 = kb[6], k7 = kb[7], k8 = kb[8];

    // ---- phase A: stage x tile + halo 3 (circular wrap; 128 = pow2) ----
    for (int i = tid; i < 70 * 70; i += 256) {
        int r = i / 70, c = i - r * 70;
        int gy = (ty + r - 3) & 127;
        int gx = (tx + c - 3) & 127;
        xs[r][c] = xsamp[gy * 128 + gx];
    }
    __syncthreads();

    // ---- phase B: blur -> xb (tile-local rows -2..65), zero outside image ----
    for (int i = tid; i < 68 * 68; i += 256) {
        int r = i / 68, c = i - r * 68;
        int gy = ty + r - 2, gx = tx + c - 2;
        float v = 0.f;
        if (gy >= 0 && gy < 128 && gx >= 0 && gx < 128) {
            v = k0 * xs[r][c];
            v = fmaf(k1, xs[r    ][c + 1], v);
            v = fmaf(k2, xs[r    ][c + 2], v);
            v = fmaf(k3, xs[r + 1][c    ], v);
            v = fmaf(k4, xs[r + 1][c + 1], v);
            v = fmaf(k5, xs[r + 1][c + 2], v);
            v = fmaf(k6, xs[r + 2][c    ], v);
            v = fmaf(k7, xs[r + 2][c + 1], v);
            v = fmaf(k8, xs[r + 2][c + 2], v);
        }
        xb[r][c] = v;
    }
    __syncthreads();

    // ---- phase C: per-thread 8x8 blurred patch into registers (b128 reads) ----
    const int ry = tid >> 4, rx = tid & 15;   // 16x16 thread grid
    const int py0 = ry * 4, px0 = rx * 4;     // tile-local output origin

    float rxb[8][8];
#pragma unroll
    for (int i = 0; i < 8; ++i) {
        const float4 lo = *reinterpret_cast<const float4*>(&xb[py0 + i][px0]);
        const float4 hi = *reinterpret_cast<const float4*>(&xb[py0 + i][px0 + 4]);
        rxb[i][0] = lo.x; rxb[i][1] = lo.y; rxb[i][2] = lo.z; rxb[i][3] = lo.w;
        rxb[i][4] = hi.x; rxb[i][5] = hi.y; rxb[i][6] = hi.z; rxb[i][7] = hi.w;
    }

    // h-position validity as additive bias: valid -> 0, invalid -> -1e30
    // (h local (i,j) sits at global (ty+py0-1+i, tx+px0-1+j))
    float rowneg[6], colneg[6];
#pragma unroll
    for (int i = 0; i < 6; ++i) {
        int gy = ty + py0 - 1 + i;
        rowneg[i] = (gy >= 0 && gy < 128) ? 0.f : -1e30f;
        int gx = tx + px0 - 1 + i;
        colneg[i] = (gx >= 0 && gx < 128) ? 0.f : -1e30f;
    }

    float acc[4][4];
#pragma unroll
    for (int a = 0; a < 4; ++a)
#pragma unroll
        for (int b_ = 0; b_ < 4; ++b_) acc[a][b_] = 0.f;

    // ---- channel loop: fully register-resident, all-FMA ----
#pragma unroll 2
    for (int c = 0; c < 64; ++c) {
        const float* __restrict__ w1c = w1 + c * 9;
        const float* __restrict__ w2c = w2 + c * 9;
        const float hinit = b1[c] + tn;
        const float u0 = w1c[0], u1 = w1c[1], u2 = w1c[2],
                    u3 = w1c[3], u4 = w1c[4], u5 = w1c[5],
                    u6 = w1c[6], u7 = w1c[7], u8 = w1c[8];
        const float v0 = w2c[0], v1 = w2c[1], v2 = w2c[2],
                    v3 = w2c[3], v4 = w2c[4], v5 = w2c[5],
                    v6 = w2c[6], v7 = w2c[7], v8 = w2c[8];

        float h[6][6];
#pragma unroll
        for (int i = 0; i < 6; ++i) {
            const float hb_i = hinit + rowneg[i];
#pragma unroll
            for (int j = 0; j < 6; ++j) {
                float vv = hb_i + colneg[j];
                vv = fmaf(u0, rxb[i    ][j    ], vv);
                vv = fmaf(u1, rxb[i    ][j + 1], vv);
                vv = fmaf(u2, rxb[i    ][j + 2], vv);
                vv = fmaf(u3, rxb[i + 1][j    ], vv);
                vv = fmaf(u4, rxb[i + 1][j + 1], vv);
                vv = fmaf(u5, rxb[i + 1][j + 2], vv);
                vv = fmaf(u6, rxb[i + 2][j    ], vv);
                vv = fmaf(u7, rxb[i + 2][j + 1], vv);
                vv = fmaf(u8, rxb[i + 2][j + 2], vv);
                h[i][j] = fmaxf(vv, 0.f);   // invalid positions: vv ~ -1e30 -> 0
            }
        }
#pragma unroll
        for (int oy = 0; oy < 4; ++oy) {
#pragma unroll
            for (int ox = 0; ox < 4; ++ox) {
                float a = acc[oy][ox];
                a = fmaf(v0, h[oy    ][ox    ], a);
                a = fmaf(v1, h[oy    ][ox + 1], a);
                a = fmaf(v2, h[oy    ][ox + 2], a);
                a = fmaf(v3, h[oy + 1][ox    ], a);
                a = fmaf(v4, h[oy + 1][ox + 1], a);
                a = fmaf(v5, h[oy + 1][ox + 2], a);
                a = fmaf(v6, h[oy + 2][ox    ], a);
                a = fmaf(v7, h[oy + 2][ox + 1], a);
                a = fmaf(v8, h[oy + 2][ox + 2], a);
                acc[oy][ox] = a;
            }
        }
    }

    // ---- epilogue: MSE vs original x (still in xs), block reduce ----
    const float b2v = b2[0];
    float sum = 0.f;
#pragma unroll
    for (int oy = 0; oy < 4; ++oy)
#pragma unroll
        for (int ox = 0; ox < 4; ++ox) {
            float recon = acc[oy][ox] + b2v;
            float xv = xs[py0 + oy + 3][px0 + ox + 3];
            float d = xv - recon;
            sum = fmaf(d, d, sum);
        }

#pragma unroll
    for (int off = 32; off > 0; off >>= 1)
        sum += __shfl_down(sum, off, 64);

    const int lane = tid & 63, wv = tid >> 6;
    if (lane == 0) redbuf[wv] = sum;
    __syncthreads();
    if (tid == 0) {
        float tot = redbuf[0] + redbuf[1] + redbuf[2] + redbuf[3];
        atomicAdd(out, tot * (1.f / 1048576.f));   // /(64*128*128)
    }
}

extern "C" void kernel_launch(void* const* d_in, const int* in_sizes, int n_in,
                              void* d_out, int out_size, void* d_ws, size_t ws_size,
                              hipStream_t stream) {
    const float* x       = (const float*)d_in[0];
    const int*   t       = (const int*)  d_in[1];
    const float* kernels = (const float*)d_in[2];
    const float* w1      = (const float*)d_in[3];
    const float* b1      = (const float*)d_in[4];
    const float* w2      = (const float*)d_in[5];
    const float* b2      = (const float*)d_in[6];
    float* out = (float*)d_out;

    hipMemsetAsync(out, 0, sizeof(float), stream);
    ddpm_fused<<<256, 256, 0, stream>>>(x, t, kernels, w1, b1, w2, b2, out);
}